// Round 1
// baseline (423.164 us; speedup 1.0000x reference)
//
#include <hip/hip_runtime.h>
#include <math.h>

#define F_    16
#define NROW  2000
#define NL    500
#define D     32
#define ROWS  (F_*NROW)   // 32000
#define SLOPE 0.2f
#define CAP   128         // global nz capacity per row (mean ~40, 14 sigma safe)
#define LCAP  256         // LDS nz capacity per row

// ---------------- K1: g = x @ w3^T + b3 ; s_l = g.a_l ; s_r = g.a_r ----------
__global__ __launch_bounds__(256) void k1_g(
    const float* __restrict__ state, const float* __restrict__ left,
    const float* __restrict__ w3, const float* __restrict__ b3,
    const float* __restrict__ attn_w,
    float* __restrict__ g, float* __restrict__ s_l, float* __restrict__ s_r)
{
    __shared__ float sw3[D*D];
    __shared__ float sb3[D], sal[D], sar[D];
    int t = threadIdx.x;
    for (int k = t; k < D*D; k += 256) sw3[k] = w3[k];
    if (t < D) { sb3[t] = b3[t]; sal[t] = attn_w[t]; sar[t] = attn_w[D + t]; }
    __syncthreads();
    int row = blockIdx.x * 256 + t;
    if (row >= ROWS) return;
    int b = row / NROW, i = row - b * NROW;
    const float* xrow = (i < NL) ? (left  + ((size_t)b * NL + i) * D)
                                 : (state + ((size_t)b * (NROW - NL) + (i - NL)) * D);
    float x[D];
#pragma unroll
    for (int k = 0; k < D/4; ++k) {
        float4 v = reinterpret_cast<const float4*>(xrow)[k];
        x[4*k] = v.x; x[4*k+1] = v.y; x[4*k+2] = v.z; x[4*k+3] = v.w;
    }
    float sl = 0.f, sr = 0.f;
    float ob[4];
    float* grow = g + (size_t)row * D;
#pragma unroll
    for (int d = 0; d < D; ++d) {
        float acc = sb3[d];
#pragma unroll
        for (int k = 0; k < D; ++k) acc += x[k] * sw3[d*D + k];
        sl += acc * sal[d]; sr += acc * sar[d];
        ob[d & 3] = acc;
        if ((d & 3) == 3)
            reinterpret_cast<float4*>(grow)[d >> 2] = make_float4(ob[0], ob[1], ob[2], ob[3]);
    }
    s_l[row] = sl; s_r[row] = sr;
}

// ---------------- K1b: w4t[j][o] = w4[o][j] ---------------------------------
__global__ __launch_bounds__(256) void k1b_w4t(const float* __restrict__ w4,
                                               float* __restrict__ w4t)
{
    int t = blockIdx.x * 256 + threadIdx.x;
    if (t < D * NROW) {
        int o = t / NROW, j = t - o * NROW;
        w4t[j * D + o] = w4[t];
    }
}

// ---------------- K2: stream mask once: compact nz, compute h ----------------
// wave-per-row; ballot-compaction is deterministic (fixed lane order)
__global__ __launch_bounds__(256) void k2_scan(
    const float* __restrict__ adj,
    const float* __restrict__ s_l, const float* __restrict__ s_r,
    const float* __restrict__ w4t, const float* __restrict__ b4,
    float* __restrict__ h, int* __restrict__ nzc, unsigned short* __restrict__ nzi)
{
    __shared__ int   sh_j[4][LCAP];
    __shared__ float sh_e[4][LCAP];
    int t = threadIdx.x;
    int w = t >> 6, lane = t & 63;
    int row = blockIdx.x * 4 + w;
    int b = row / NROW, i = row - b * NROW;
    int r = i & 15;
    const float4* mrow = reinterpret_cast<const float4*>(adj + (size_t)row * NROW);
    unsigned long long lmask = (1ull << lane) - 1ull;
    int cnt = 0;
#pragma unroll
    for (int it = 0; it < 8; ++it) {
        int idx4 = it * 64 + lane;
        float4 v = make_float4(0.f, 0.f, 0.f, 0.f);
        if (idx4 < NROW/4) v = mrow[idx4];
#pragma unroll
        for (int c = 0; c < 4; ++c) {
            float val = (c == 0) ? v.x : (c == 1) ? v.y : (c == 2) ? v.z : v.w;
            bool p = (val != 0.0f);
            unsigned long long m = __ballot(p);
            if (p) {
                int pos = cnt + __popcll(m & lmask);
                if (pos < LCAP) sh_j[w][pos] = idx4 * 4 + c;
            }
            cnt += __popcll(m);
        }
    }
    if (cnt > LCAP) cnt = LCAP;
    __syncthreads();
    // e values for this row's nonzeros (gathers hit L2: s_l/s_r are 256 KB)
    const float* slb = s_l + (size_t)b * NROW;
    const float* srr = s_r + (size_t)r * NROW;
    for (int k = lane; k < cnt; k += 64) {
        int j = sh_j[w][k];
        float e = slb[j] + srr[j];
        sh_e[w][k] = (e > 0.f) ? e : SLOPE * e;
    }
    __syncthreads();
    // h[row][o] = lrelu(sum_k e_k * w4t[j_k][o] + b4[o])
    int o = lane & 31, half = lane >> 5;
    float acc = 0.f;
    for (int k = half; k < cnt; k += 2)
        acc += sh_e[w][k] * w4t[sh_j[w][k] * D + o];
    acc += __shfl_xor(acc, 32, 64);
    if (lane < 32) {
        float hv = acc + b4[o];
        h[(size_t)row * D + o] = (hv > 0.f) ? hv : SLOPE * hv;
    }
    // persist nz list for the agg pass
    int cc = (cnt < CAP) ? cnt : CAP;
    for (int k = lane; k < cc; k += 64)
        nzi[(size_t)row * CAP + k] = (unsigned short)sh_j[w][k];
    if (lane == 0) nzc[row] = cc;
}

// ---------------- K3a: partial sums of exp(h) over row-slices ----------------
// |h| is O(1): softmax without max-subtract is numerically safe & identical
__global__ __launch_bounds__(256) void k3a_psum(const float* __restrict__ h,
                                                float* __restrict__ psum)
{
    int b = blockIdx.x, slice = blockIdx.y;
    int t = threadIdx.x;
    int o = t & 31, ti = t >> 5;   // 8 row-groups
    int base = slice * 250;
    float s = 0.f;
    for (int i = base + ti; i < base + 250; i += 8)
        s += expf(h[((size_t)b * NROW + i) * D + o]);
    __shared__ float red[8][D];
    red[ti][o] = s;
    __syncthreads();
    if (t < D) {
        float tot = 0.f;
#pragma unroll
        for (int k = 0; k < 8; ++k) tot += red[k][t];
        psum[((size_t)b * 8 + slice) * D + t] = tot;
    }
}

// ---------------- K3b: st = (softmax(h)*g) @ w1^T + b1 -----------------------
__global__ __launch_bounds__(256) void k3b_st(
    const float* __restrict__ h, const float* __restrict__ g,
    const float* __restrict__ psum,
    const float* __restrict__ w1, const float* __restrict__ b1,
    float* __restrict__ st)
{
    __shared__ float sw1[D*D], sb1[D], ssum[D];
    int t = threadIdx.x;
    int b = blockIdx.y, chunk = blockIdx.x;
    for (int k = t; k < D*D; k += 256) sw1[k] = w1[k];
    if (t < D) {
        sb1[t] = b1[t];
        float tot = 0.f;
#pragma unroll
        for (int s = 0; s < 8; ++s) tot += psum[((size_t)b * 8 + s) * D + t];
        ssum[t] = tot;
    }
    __syncthreads();
    if (t >= 250) return;
    size_t row = (size_t)b * NROW + chunk * 250 + t;
    const float* hrow = h + row * D;
    const float* grow = g + row * D;
    float p[D];
#pragma unroll
    for (int k = 0; k < D; ++k)
        p[k] = (expf(hrow[k]) / ssum[k]) * grow[k];
    float* strow = st + row * D;
    float ob[4];
#pragma unroll
    for (int d = 0; d < D; ++d) {
        float acc = sb1[d];
#pragma unroll
        for (int k = 0; k < D; ++k) acc += p[k] * sw1[d*D + k];
        ob[d & 3] = acc;
        if ((d & 3) == 3)
            reinterpret_cast<float4*>(strow)[d >> 2] = make_float4(ob[0], ob[1], ob[2], ob[3]);
    }
}

// ---------------- K4: agg gather + LN + gates + c1 + final matvec ------------
__global__ __launch_bounds__(256) void k4_final(
    const float* __restrict__ st,
    const int* __restrict__ nzc, const unsigned short* __restrict__ nzi,
    const float* __restrict__ w_ih, const float* __restrict__ b_ih,
    const float* __restrict__ b_hh,
    const float* __restrict__ ln_g, const float* __restrict__ ln_b,
    const float* __restrict__ w2, const float* __restrict__ b2,
    float* __restrict__ out)
{
    __shared__ float swih[96*D];
    __shared__ float sbg[96];
    __shared__ float sw2[D*D];
    __shared__ float sb2[D], slg[D], slb[D];
    int t = threadIdx.x;
    for (int k = t; k < 96*D; k += 256) swih[k] = w_ih[k];
    for (int k = t; k < D*D; k += 256) sw2[k] = w2[k];
    if (t < 96) sbg[t] = b_ih[t] + b_hh[t];
    if (t < D) { sb2[t] = b2[t]; slg[t] = ln_g[t]; slb[t] = ln_b[t]; }
    __syncthreads();
    int row = blockIdx.x * 256 + t;
    if (row >= ROWS) return;
    int b = row / NROW;
    int cnt = nzc[row];
    const unsigned short* lst = nzi + (size_t)row * CAP;
    float agg[D];
#pragma unroll
    for (int d = 0; d < D; ++d) agg[d] = 0.f;
    const float* stb = st + (size_t)b * NROW * D;
    for (int k = 0; k < cnt; ++k) {
        const float* srow = stb + (size_t)lst[k] * D;   // mask value is exactly 1.0
#pragma unroll
        for (int q = 0; q < D/4; ++q) {
            float4 v = reinterpret_cast<const float4*>(srow)[q];
            agg[4*q] += v.x; agg[4*q+1] += v.y; agg[4*q+2] += v.z; agg[4*q+3] += v.w;
        }
    }
    float s[D];
    const float* strow = st + (size_t)row * D;
#pragma unroll
    for (int q = 0; q < D/4; ++q) {
        float4 v = reinterpret_cast<const float4*>(strow)[q];
        s[4*q] = v.x; s[4*q+1] = v.y; s[4*q+2] = v.z; s[4*q+3] = v.w;
    }
    // layernorm stats (biased var, matches jnp.var)
    float m = 0.f;
#pragma unroll
    for (int d = 0; d < D; ++d) m += s[d];
    m *= (1.f / D);
    float var = 0.f;
#pragma unroll
    for (int d = 0; d < D; ++d) { float dd = s[d] - m; var += dd * dd; }
    var *= (1.f / D);
    float inv = 1.f / sqrtf(var + 1e-6f);
    // gates (q, q+32, q+64 rows of w_ih), c1, orow in-place into s[] (static idx)
#pragma unroll
    for (int q = 0; q < D; ++q) {
        float gi = sbg[q], gf = sbg[q+32], gg = sbg[q+64];
#pragma unroll
        for (int d = 0; d < D; ++d) {
            gi += swih[q*D + d]      * agg[d];
            gf += swih[(q+32)*D + d] * agg[d];
            gg += swih[(q+64)*D + d] * agg[d];
        }
        float ig  = 1.f / (1.f + expf(-gi));
        float fg  = 1.f / (1.f + expf(-gf));
        float g_g = tanhf(gg);
        float nx  = slg[q] * (s[q] - m) * inv + slb[q];
        s[q] = s[q] + fg * nx + ig * g_g;
    }
    float* orow = out + (size_t)row * D;
    float ob[4];
#pragma unroll
    for (int d = 0; d < D; ++d) {
        float acc = sb2[d];
#pragma unroll
        for (int k = 0; k < D; ++k) acc += sw2[d*D + k] * s[k];
        ob[d & 3] = acc;
        if ((d & 3) == 3)
            reinterpret_cast<float4*>(orow)[d >> 2] = make_float4(ob[0], ob[1], ob[2], ob[3]);
    }
}

// ---------------------------------------------------------------------------
extern "C" void kernel_launch(void* const* d_in, const int* in_sizes, int n_in,
                              void* d_out, int out_size, void* d_ws, size_t ws_size,
                              hipStream_t stream)
{
    const float* state  = (const float*)d_in[0];
    const float* left   = (const float*)d_in[1];
    const float* adj    = (const float*)d_in[2];
    const float* w3     = (const float*)d_in[3];
    const float* b3     = (const float*)d_in[4];
    const float* attn_w = (const float*)d_in[5];
    const float* w4     = (const float*)d_in[6];
    const float* b4     = (const float*)d_in[7];
    const float* w1     = (const float*)d_in[8];
    const float* b1     = (const float*)d_in[9];
    const float* w_ih   = (const float*)d_in[10];
    // d_in[11] = w_hh: unused by the reference math (only b_hh enters gates)
    const float* b_ih   = (const float*)d_in[12];
    const float* b_hh   = (const float*)d_in[13];
    const float* ln_g   = (const float*)d_in[14];
    const float* ln_b   = (const float*)d_in[15];
    const float* w2     = (const float*)d_in[16];
    const float* b2     = (const float*)d_in[17];
    float* out = (float*)d_out;

    // workspace layout (21.2 MB total)
    float* g    = (float*)d_ws;                 // 1,024,000
    float* h    = g  + (size_t)ROWS * D;        // 1,024,000
    float* st   = h  + (size_t)ROWS * D;        // 1,024,000
    float* s_l  = st + (size_t)ROWS * D;        // 32,000
    float* s_r  = s_l + ROWS;                   // 32,000
    float* w4t  = s_r + ROWS;                   // 64,000
    float* psum = w4t + (size_t)NROW * D;       // 16*8*32
    int*   nzc  = (int*)(psum + F_ * 8 * D);    // 32,000 int
    unsigned short* nzi = (unsigned short*)(nzc + ROWS); // 32,000*128 u16

    k1_g   <<<dim3(ROWS/256),           dim3(256), 0, stream>>>(state, left, w3, b3, attn_w, g, s_l, s_r);
    k1b_w4t<<<dim3((D*NROW+255)/256),   dim3(256), 0, stream>>>(w4, w4t);
    k2_scan<<<dim3(ROWS/4),             dim3(256), 0, stream>>>(adj, s_l, s_r, w4t, b4, h, nzc, nzi);
    k3a_psum<<<dim3(F_, 8),             dim3(256), 0, stream>>>(h, psum);
    k3b_st <<<dim3(8, F_),              dim3(256), 0, stream>>>(h, g, psum, w1, b1, st);
    k4_final<<<dim3(ROWS/256),          dim3(256), 0, stream>>>(st, nzc, nzi, w_ih, b_ih, b_hh,
                                                                ln_g, ln_b, w2, b2, out);
}

// Round 2
// 153.030 us; speedup vs baseline: 2.7652x; 2.7652x over previous
//
#include <hip/hip_runtime.h>
#include <math.h>

#define F_    16
#define NROW  2000
#define NL    500
#define D     32
#define ROWS  (F_*NROW)   // 32000
#define SLOPE 0.2f
#define CAP   128         // global nz capacity per row (mean ~40, 14 sigma safe)
#define LCAP  256         // LDS nz capacity per row

// ---------------- K1: g = x @ w3^T + b3 ; s_l = g.a_l ; s_r = g.a_r ----------
__global__ __launch_bounds__(256) void k1_g(
    const float* __restrict__ state, const float* __restrict__ left,
    const float* __restrict__ w3, const float* __restrict__ b3,
    const float* __restrict__ attn_w,
    float* __restrict__ g, float* __restrict__ s_l, float* __restrict__ s_r)
{
    __shared__ float sw3[D*D];
    __shared__ float sb3[D], sal[D], sar[D];
    int t = threadIdx.x;
    for (int k = t; k < D*D; k += 256) sw3[k] = w3[k];
    if (t < D) { sb3[t] = b3[t]; sal[t] = attn_w[t]; sar[t] = attn_w[D + t]; }
    __syncthreads();
    int row = blockIdx.x * 256 + t;
    if (row >= ROWS) return;
    int b = row / NROW, i = row - b * NROW;
    const float* xrow = (i < NL) ? (left  + ((size_t)b * NL + i) * D)
                                 : (state + ((size_t)b * (NROW - NL) + (i - NL)) * D);
    float x[D];
#pragma unroll
    for (int k = 0; k < D/4; ++k) {
        float4 v = reinterpret_cast<const float4*>(xrow)[k];
        x[4*k] = v.x; x[4*k+1] = v.y; x[4*k+2] = v.z; x[4*k+3] = v.w;
    }
    float sl = 0.f, sr = 0.f;
    float ob[4];
    float* grow = g + (size_t)row * D;
#pragma unroll
    for (int d = 0; d < D; ++d) {
        float acc = sb3[d];
#pragma unroll
        for (int k = 0; k < D; ++k) acc += x[k] * sw3[d*D + k];
        sl += acc * sal[d]; sr += acc * sar[d];
        ob[d & 3] = acc;
        if ((d & 3) == 3)
            reinterpret_cast<float4*>(grow)[d >> 2] = make_float4(ob[0], ob[1], ob[2], ob[3]);
    }
    s_l[row] = sl; s_r[row] = sr;
}

// ---------------- K1b: w4t[j][o] = w4[o][j] ---------------------------------
__global__ __launch_bounds__(256) void k1b_w4t(const float* __restrict__ w4,
                                               float* __restrict__ w4t)
{
    int t = blockIdx.x * 256 + threadIdx.x;
    if (t < D * NROW) {
        int o = t / NROW, j = t - o * NROW;
        w4t[j * D + o] = w4[t];
    }
}

// ---------------- K2: stream mask once: compact nz, compute h ----------------
// wave-per-row; ballot-compaction is deterministic (fixed lane order)
__global__ __launch_bounds__(256) void k2_scan(
    const float* __restrict__ adj,
    const float* __restrict__ s_l, const float* __restrict__ s_r,
    const float* __restrict__ w4t, const float* __restrict__ b4,
    float* __restrict__ h, int* __restrict__ nzc, unsigned short* __restrict__ nzi)
{
    __shared__ int   sh_j[4][LCAP];
    __shared__ float sh_e[4][LCAP];
    int t = threadIdx.x;
    int w = t >> 6, lane = t & 63;
    int row = blockIdx.x * 4 + w;
    int b = row / NROW, i = row - b * NROW;
    int r = i & 15;
    const float4* mrow = reinterpret_cast<const float4*>(adj + (size_t)row * NROW);
    unsigned long long lmask = (1ull << lane) - 1ull;
    int cnt = 0;
#pragma unroll
    for (int it = 0; it < 8; ++it) {
        int idx4 = it * 64 + lane;
        float4 v = make_float4(0.f, 0.f, 0.f, 0.f);
        if (idx4 < NROW/4) v = mrow[idx4];
#pragma unroll
        for (int c = 0; c < 4; ++c) {
            float val = (c == 0) ? v.x : (c == 1) ? v.y : (c == 2) ? v.z : v.w;
            bool p = (val != 0.0f);
            unsigned long long m = __ballot(p);
            if (p) {
                int pos = cnt + __popcll(m & lmask);
                if (pos < LCAP) sh_j[w][pos] = idx4 * 4 + c;
            }
            cnt += __popcll(m);
        }
    }
    if (cnt > LCAP) cnt = LCAP;
    __syncthreads();
    // e values for this row's nonzeros (gathers hit L2: s_l/s_r are 256 KB)
    const float* slb = s_l + (size_t)b * NROW;
    const float* srr = s_r + (size_t)r * NROW;
    for (int k = lane; k < cnt; k += 64) {
        int j = sh_j[w][k];
        float e = slb[j] + srr[j];
        sh_e[w][k] = (e > 0.f) ? e : SLOPE * e;
    }
    __syncthreads();
    // h[row][o] = lrelu(sum_k e_k * w4t[j_k][o] + b4[o])
    int o = lane & 31, half = lane >> 5;
    float acc = 0.f;
    for (int k = half; k < cnt; k += 2)
        acc += sh_e[w][k] * w4t[sh_j[w][k] * D + o];
    acc += __shfl_xor(acc, 32, 64);
    if (lane < 32) {
        float hv = acc + b4[o];
        h[(size_t)row * D + o] = (hv > 0.f) ? hv : SLOPE * hv;
    }
    // persist nz list for the agg pass
    int cc = (cnt < CAP) ? cnt : CAP;
    for (int k = lane; k < cc; k += 64)
        nzi[(size_t)row * CAP + k] = (unsigned short)sh_j[w][k];
    if (lane == 0) nzc[row] = cc;
}

// ---------------- K3a: partial sums of exp(h) over row-slices ----------------
__global__ __launch_bounds__(256) void k3a_psum(const float* __restrict__ h,
                                                float* __restrict__ psum)
{
    int b = blockIdx.x, slice = blockIdx.y;
    int t = threadIdx.x;
    int o = t & 31, ti = t >> 5;   // 8 row-groups
    int base = slice * 250;
    float s = 0.f;
    for (int i = base + ti; i < base + 250; i += 8)
        s += expf(h[((size_t)b * NROW + i) * D + o]);
    __shared__ float red[8][D];
    red[ti][o] = s;
    __syncthreads();
    if (t < D) {
        float tot = 0.f;
#pragma unroll
        for (int k = 0; k < 8; ++k) tot += red[k][t];
        psum[((size_t)b * 8 + slice) * D + t] = tot;
    }
}

// ---------------- K3b: st = (softmax(h)*g) @ w1^T + b1 -----------------------
__global__ __launch_bounds__(256) void k3b_st(
    const float* __restrict__ h, const float* __restrict__ g,
    const float* __restrict__ psum,
    const float* __restrict__ w1, const float* __restrict__ b1,
    float* __restrict__ st)
{
    __shared__ float sw1[D*D], sb1[D], ssum[D];
    int t = threadIdx.x;
    int b = blockIdx.y, chunk = blockIdx.x;
    for (int k = t; k < D*D; k += 256) sw1[k] = w1[k];
    if (t < D) {
        sb1[t] = b1[t];
        float tot = 0.f;
#pragma unroll
        for (int s = 0; s < 8; ++s) tot += psum[((size_t)b * 8 + s) * D + t];
        ssum[t] = tot;
    }
    __syncthreads();
    if (t >= 250) return;
    size_t row = (size_t)b * NROW + chunk * 250 + t;
    const float* hrow = h + row * D;
    const float* grow = g + row * D;
    float p[D];
#pragma unroll
    for (int k = 0; k < D; ++k)
        p[k] = (expf(hrow[k]) / ssum[k]) * grow[k];
    float* strow = st + row * D;
    float ob[4];
#pragma unroll
    for (int d = 0; d < D; ++d) {
        float acc = sb1[d];
#pragma unroll
        for (int k = 0; k < D; ++k) acc += p[k] * sw1[d*D + k];
        ob[d & 3] = acc;
        if ((d & 3) == 3)
            reinterpret_cast<float4*>(strow)[d >> 2] = make_float4(ob[0], ob[1], ob[2], ob[3]);
    }
}

// ---------------- K4: agg gather + LN + gates + c1 + final matvec ------------
// 32-lane group per row (lane = feature d); 8 rows per 256-thread block.
// No per-thread arrays -> no spills. Cross-lane dots staged through LDS
// (weights padded to stride 33 to avoid 32-way bank conflicts on column reads).
__global__ __launch_bounds__(256) void k4_final(
    const float* __restrict__ st,
    const int* __restrict__ nzc, const unsigned short* __restrict__ nzi,
    const float* __restrict__ w_ih, const float* __restrict__ b_ih,
    const float* __restrict__ b_hh,
    const float* __restrict__ ln_g, const float* __restrict__ ln_b,
    const float* __restrict__ w2, const float* __restrict__ b2,
    float* __restrict__ out)
{
    __shared__ float swih[96*33];          // padded
    __shared__ float sw2[D*33];            // padded
    __shared__ float sbg[96];
    __shared__ float sb2[D], slg[D], slb[D];
    __shared__ unsigned short jl[8][CAP];
    __shared__ float aggsh[8][D];
    __shared__ float s2sh[8][D];

    int t = threadIdx.x;
    for (int k = t; k < 96*D; k += 256) swih[(k/D)*33 + (k%D)] = w_ih[k];
    for (int k = t; k < D*D;  k += 256) sw2 [(k/D)*33 + (k%D)] = w2[k];
    if (t < 96) sbg[t] = b_ih[t] + b_hh[t];
    if (t < D) { sb2[t] = b2[t]; slg[t] = ln_g[t]; slb[t] = ln_b[t]; }

    int grp = t >> 5, lane = t & 31;
    int row = blockIdx.x * 8 + grp;
    int b = row / NROW;
    int cnt = nzc[row];
    const unsigned short* lst = nzi + (size_t)row * CAP;
    for (int k = lane; k < cnt; k += 32) jl[grp][k] = lst[k];
    __syncthreads();

    // agg[lane] = sum over nz rows of st[b][j][lane]  (coalesced 128B loads)
    const float* stb = st + (size_t)b * NROW * D;
    float agg = 0.f;
    int k = 0;
    for (; k + 4 <= cnt; k += 4) {
        int j0 = jl[grp][k], j1 = jl[grp][k+1], j2 = jl[grp][k+2], j3 = jl[grp][k+3];
        float a0 = stb[j0*D + lane], a1 = stb[j1*D + lane];
        float a2 = stb[j2*D + lane], a3 = stb[j3*D + lane];
        agg += (a0 + a1) + (a2 + a3);
    }
    for (; k < cnt; ++k) agg += stb[jl[grp][k]*D + lane];

    float sv = st[(size_t)row * D + lane];

    // layernorm stats across the 32-lane group
    float sum = sv;
#pragma unroll
    for (int m = 16; m >= 1; m >>= 1) sum += __shfl_xor(sum, m, 32);
    float mean = sum * (1.f / D);
    float dd = sv - mean;
    float vs = dd * dd;
#pragma unroll
    for (int m = 16; m >= 1; m >>= 1) vs += __shfl_xor(vs, m, 32);
    float inv = 1.f / sqrtf(vs * (1.f / D) + 1e-6f);
    float nx = slg[lane] * dd * inv + slb[lane];

    aggsh[grp][lane] = agg;
    __syncthreads();

    // gates: lane q computes rows q, q+32, q+64 of w_ih  (LDS broadcast reads)
    float gi = sbg[lane], gf = sbg[lane + 32], gg = sbg[lane + 64];
#pragma unroll
    for (int d = 0; d < D; ++d) {
        float a = aggsh[grp][d];
        gi += swih[lane*33 + d]      * a;
        gf += swih[(lane+32)*33 + d] * a;
        gg += swih[(lane+64)*33 + d] * a;
    }
    float ig  = 1.f / (1.f + expf(-gi));
    float fg  = 1.f / (1.f + expf(-gf));
    float g_g = tanhf(gg);
    float s2  = sv + fg * nx + ig * g_g;

    s2sh[grp][lane] = s2;
    __syncthreads();

    // out[row][lane] = b2 + sum_k w2[lane][k] * s2[k]
    float acc = sb2[lane];
#pragma unroll
    for (int q = 0; q < D; ++q) acc += sw2[lane*33 + q] * s2sh[grp][q];
    out[(size_t)row * D + lane] = acc;
}

// ---------------------------------------------------------------------------
extern "C" void kernel_launch(void* const* d_in, const int* in_sizes, int n_in,
                              void* d_out, int out_size, void* d_ws, size_t ws_size,
                              hipStream_t stream)
{
    const float* state  = (const float*)d_in[0];
    const float* left   = (const float*)d_in[1];
    const float* adj    = (const float*)d_in[2];
    const float* w3     = (const float*)d_in[3];
    const float* b3     = (const float*)d_in[4];
    const float* attn_w = (const float*)d_in[5];
    const float* w4     = (const float*)d_in[6];
    const float* b4     = (const float*)d_in[7];
    const float* w1     = (const float*)d_in[8];
    const float* b1     = (const float*)d_in[9];
    const float* w_ih   = (const float*)d_in[10];
    // d_in[11] = w_hh: unused by the reference math (only b_hh enters gates)
    const float* b_ih   = (const float*)d_in[12];
    const float* b_hh   = (const float*)d_in[13];
    const float* ln_g   = (const float*)d_in[14];
    const float* ln_b   = (const float*)d_in[15];
    const float* w2     = (const float*)d_in[16];
    const float* b2     = (const float*)d_in[17];
    float* out = (float*)d_out;

    // workspace layout (21.2 MB total)
    float* g    = (float*)d_ws;                 // 1,024,000
    float* h    = g  + (size_t)ROWS * D;        // 1,024,000
    float* st   = h  + (size_t)ROWS * D;        // 1,024,000
    float* s_l  = st + (size_t)ROWS * D;        // 32,000
    float* s_r  = s_l + ROWS;                   // 32,000
    float* w4t  = s_r + ROWS;                   // 64,000
    float* psum = w4t + (size_t)NROW * D;       // 16*8*32
    int*   nzc  = (int*)(psum + F_ * 8 * D);    // 32,000 int
    unsigned short* nzi = (unsigned short*)(nzc + ROWS); // 32,000*128 u16

    k1_g   <<<dim3(ROWS/256),           dim3(256), 0, stream>>>(state, left, w3, b3, attn_w, g, s_l, s_r);
    k1b_w4t<<<dim3((D*NROW+255)/256),   dim3(256), 0, stream>>>(w4, w4t);
    k2_scan<<<dim3(ROWS/4),             dim3(256), 0, stream>>>(adj, s_l, s_r, w4t, b4, h, nzc, nzi);
    k3a_psum<<<dim3(F_, 8),             dim3(256), 0, stream>>>(h, psum);
    k3b_st <<<dim3(8, F_),              dim3(256), 0, stream>>>(h, g, psum, w1, b1, st);
    k4_final<<<dim3(ROWS/8),            dim3(256), 0, stream>>>(st, nzc, nzi, w_ih, b_ih, b_hh,
                                                                ln_g, ln_b, w2, b2, out);
}

// Round 3
// 141.761 us; speedup vs baseline: 2.9850x; 1.0795x over previous
//
#include <hip/hip_runtime.h>
#include <math.h>

#define F_    16
#define NROW  2000
#define NL    500
#define D     32
#define ROWS  (F_*NROW)   // 32000
#define SLOPE 0.2f
#define CAP   128         // global nz capacity per row (mean ~40)
#define LCAP  256         // LDS nz capacity per row

// ---------------- K1: g = x@w3^T+b3 ; s_l,s_r ; (+w4 transpose blocks) ------
// 32-lane group per row, lane = output feature d. 8 rows/block, 4000 blocks;
// blocks >= 4000 transpose w4 -> w4t.
__global__ __launch_bounds__(256) void k1_g(
    const float* __restrict__ state, const float* __restrict__ left,
    const float* __restrict__ w3, const float* __restrict__ b3,
    const float* __restrict__ attn_w, const float* __restrict__ w4,
    float* __restrict__ g, float* __restrict__ s_l, float* __restrict__ s_r,
    float* __restrict__ w4t)
{
    int bid = blockIdx.x;
    int t = threadIdx.x;
    if (bid >= ROWS/8) {           // transpose tail: w4t[j][o] = w4[o][j]
        int k = (bid - ROWS/8) * 256 + t;
        if (k < D * NROW) {
            int o = k / NROW, j = k - o * NROW;
            w4t[j * D + o] = w4[k];
        }
        return;
    }
    __shared__ float sw3[D*33];
    __shared__ float sb3[D], sal[D], sar[D];
    for (int k = t; k < D*D; k += 256) sw3[(k>>5)*33 + (k&31)] = w3[k];
    if (t < D) { sb3[t] = b3[t]; sal[t] = attn_w[t]; sar[t] = attn_w[D + t]; }
    __syncthreads();
    int grp = t >> 5, lane = t & 31;
    int row = bid * 8 + grp;
    int b = row / NROW, i = row - b * NROW;
    const float* xrow = (i < NL) ? (left  + ((size_t)b * NL + i) * D)
                                 : (state + ((size_t)b * (NROW - NL) + (i - NL)) * D);
    float x = xrow[lane];
    float acc = sb3[lane];
#pragma unroll
    for (int k = 0; k < D; ++k)
        acc += __shfl(x, k, 32) * sw3[lane*33 + k];
    g[(size_t)row * D + lane] = acc;
    float pl = acc * sal[lane], pr = acc * sar[lane];
#pragma unroll
    for (int m = 16; m >= 1; m >>= 1) {
        pl += __shfl_xor(pl, m, 32);
        pr += __shfl_xor(pr, m, 32);
    }
    if (lane == 0) { s_l[row] = pl; s_r[row] = pr; }
}

// ---------------- K2: stream mask once: compact nz, compute h ----------------
// wave-per-row; per-wave LDS buffers -> NO cross-wave barriers needed
// (within-wave LDS RAW ordering is enforced by compiler lgkmcnt waits).
__global__ __launch_bounds__(256) void k2_scan(
    const float* __restrict__ adj,
    const float* __restrict__ s_l, const float* __restrict__ s_r,
    const float* __restrict__ w4t, const float* __restrict__ b4,
    float* __restrict__ h, int* __restrict__ nzc, unsigned short* __restrict__ nzi)
{
    __shared__ int   sh_j[4][LCAP];
    __shared__ float sh_e[4][LCAP];
    int t = threadIdx.x;
    int w = t >> 6, lane = t & 63;
    int row = blockIdx.x * 4 + w;
    int b = row / NROW, i = row - b * NROW;
    int r = i & 15;
    const float4* mrow = reinterpret_cast<const float4*>(adj + (size_t)row * NROW);
    unsigned long long lmask = (1ull << lane) - 1ull;
    int cnt = 0;
#pragma unroll
    for (int it = 0; it < 8; ++it) {
        int idx4 = it * 64 + lane;
        float4 v = make_float4(0.f, 0.f, 0.f, 0.f);
        if (idx4 < NROW/4) v = mrow[idx4];
#pragma unroll
        for (int c = 0; c < 4; ++c) {
            float val = (c == 0) ? v.x : (c == 1) ? v.y : (c == 2) ? v.z : v.w;
            bool p = (val != 0.0f);
            unsigned long long m = __ballot(p);
            if (p) {
                int pos = cnt + __popcll(m & lmask);
                if (pos < LCAP) sh_j[w][pos] = idx4 * 4 + c;
            }
            cnt += __popcll(m);
        }
    }
    if (cnt > LCAP) cnt = LCAP;
    // e values for this row's nonzeros (gathers hit L2: s_l/s_r tiny)
    const float* slb = s_l + (size_t)b * NROW;
    const float* srr = s_r + (size_t)r * NROW;
    for (int k = lane; k < cnt; k += 64) {
        int j = sh_j[w][k];
        float e = slb[j] + srr[j];
        sh_e[w][k] = (e > 0.f) ? e : SLOPE * e;
    }
    // h[row][o] = lrelu(sum_k e_k * w4t[j_k][o] + b4[o])
    int o = lane & 31, half = lane >> 5;
    float acc = 0.f;
    for (int k = half; k < cnt; k += 2)
        acc += sh_e[w][k] * w4t[sh_j[w][k] * D + o];
    acc += __shfl_xor(acc, 32, 64);
    if (lane < 32) {
        float hv = acc + b4[o];
        h[(size_t)row * D + o] = (hv > 0.f) ? hv : SLOPE * hv;
    }
    // persist nz list for the agg pass
    int cc = (cnt < CAP) ? cnt : CAP;
    for (int k = lane; k < cc; k += 64)
        nzi[(size_t)row * CAP + k] = (unsigned short)sh_j[w][k];
    if (lane == 0) nzc[row] = cc;
}

// ---------------- K3a: partial sums of exp(h), 16 slices x 16 batches --------
__global__ __launch_bounds__(256) void k3a_psum(const float* __restrict__ h,
                                                float* __restrict__ psum)
{
    int b = blockIdx.x, slice = blockIdx.y;
    int t = threadIdx.x;
    int o = t & 31, ti = t >> 5;   // 8 row-groups
    int base = slice * 125;
    float s = 0.f;
    for (int i = base + ti; i < base + 125; i += 8)
        s += expf(h[((size_t)b * NROW + i) * D + o]);
    __shared__ float red[8][D];
    red[ti][o] = s;
    __syncthreads();
    if (t < D) {
        float tot = 0.f;
#pragma unroll
        for (int k = 0; k < 8; ++k) tot += red[k][t];
        psum[((size_t)b * 16 + slice) * D + t] = tot;
    }
}

// ---------------- K3b: st = (softmax(h)*g) @ w1^T + b1 -----------------------
// 32-lane group per row; 8 rows/block, 4000 blocks (250 blocks per batch).
__global__ __launch_bounds__(256) void k3b_st(
    const float* __restrict__ h, const float* __restrict__ g,
    const float* __restrict__ psum,
    const float* __restrict__ w1, const float* __restrict__ b1,
    float* __restrict__ st)
{
    __shared__ float sw1[D*33], sb1[D], ssum[D];
    int t = threadIdx.x;
    int bid = blockIdx.x;
    int b = bid / 250;
    for (int k = t; k < D*D; k += 256) sw1[(k>>5)*33 + (k&31)] = w1[k];
    if (t < D) {
        sb1[t] = b1[t];
        float tot = 0.f;
#pragma unroll
        for (int s = 0; s < 16; ++s) tot += psum[((size_t)b * 16 + s) * D + t];
        ssum[t] = tot;
    }
    __syncthreads();
    int grp = t >> 5, lane = t & 31;
    size_t row = (size_t)bid * 8 + grp;
    float p = (expf(h[row * D + lane]) / ssum[lane]) * g[row * D + lane];
    float acc = sb1[lane];
#pragma unroll
    for (int k = 0; k < D; ++k)
        acc += __shfl(p, k, 32) * sw1[lane*33 + k];
    st[row * D + lane] = acc;
}

// ---------------- K4: agg gather + LN + gates + c1 + final matvec ------------
// 32-lane group per row; 8 rows/block. Per-group LDS -> only the weight-staging
// barrier is needed.
__global__ __launch_bounds__(256) void k4_final(
    const float* __restrict__ st,
    const int* __restrict__ nzc, const unsigned short* __restrict__ nzi,
    const float* __restrict__ w_ih, const float* __restrict__ b_ih,
    const float* __restrict__ b_hh,
    const float* __restrict__ ln_g, const float* __restrict__ ln_b,
    const float* __restrict__ w2, const float* __restrict__ b2,
    float* __restrict__ out)
{
    __shared__ float swih[96*33];          // padded
    __shared__ float sw2[D*33];            // padded
    __shared__ float sbg[96];
    __shared__ float sb2[D], slg[D], slb[D];
    __shared__ unsigned short jl[8][CAP];
    __shared__ float aggsh[8][D];
    __shared__ float s2sh[8][D];

    int t = threadIdx.x;
    for (int k = t; k < 96*D; k += 256) swih[(k/D)*33 + (k%D)] = w_ih[k];
    for (int k = t; k < D*D;  k += 256) sw2 [(k/D)*33 + (k%D)] = w2[k];
    if (t < 96) sbg[t] = b_ih[t] + b_hh[t];
    if (t < D) { sb2[t] = b2[t]; slg[t] = ln_g[t]; slb[t] = ln_b[t]; }

    int grp = t >> 5, lane = t & 31;
    int row = blockIdx.x * 8 + grp;
    int b = row / NROW;
    int cnt = nzc[row];
    const unsigned short* lst = nzi + (size_t)row * CAP;
    for (int k = lane; k < cnt; k += 32) jl[grp][k] = lst[k];
    __syncthreads();   // for the cooperatively staged weights

    // agg[lane] = sum over nz rows of st[b][j][lane]  (coalesced 128B loads)
    const float* stb = st + (size_t)b * NROW * D;
    float agg = 0.f;
    int k = 0;
    for (; k + 4 <= cnt; k += 4) {
        int j0 = jl[grp][k], j1 = jl[grp][k+1], j2 = jl[grp][k+2], j3 = jl[grp][k+3];
        float a0 = stb[j0*D + lane], a1 = stb[j1*D + lane];
        float a2 = stb[j2*D + lane], a3 = stb[j3*D + lane];
        agg += (a0 + a1) + (a2 + a3);
    }
    for (; k < cnt; ++k) agg += stb[jl[grp][k]*D + lane];

    float sv = st[(size_t)row * D + lane];

    // layernorm stats across the 32-lane group
    float sum = sv;
#pragma unroll
    for (int m = 16; m >= 1; m >>= 1) sum += __shfl_xor(sum, m, 32);
    float mean = sum * (1.f / D);
    float dd = sv - mean;
    float vs = dd * dd;
#pragma unroll
    for (int m = 16; m >= 1; m >>= 1) vs += __shfl_xor(vs, m, 32);
    float inv = 1.f / sqrtf(vs * (1.f / D) + 1e-6f);
    float nx = slg[lane] * dd * inv + slb[lane];

    aggsh[grp][lane] = agg;     // per-group buffer: within-wave ordering only

    // gates: lane q computes rows q, q+32, q+64 of w_ih (LDS broadcast reads)
    float gi = sbg[lane], gf = sbg[lane + 32], gg = sbg[lane + 64];
#pragma unroll
    for (int d = 0; d < D; ++d) {
        float a = aggsh[grp][d];
        gi += swih[lane*33 + d]      * a;
        gf += swih[(lane+32)*33 + d] * a;
        gg += swih[(lane+64)*33 + d] * a;
    }
    float ig  = 1.f / (1.f + expf(-gi));
    float fg  = 1.f / (1.f + expf(-gf));
    float g_g = tanhf(gg);
    float s2  = sv + fg * nx + ig * g_g;

    s2sh[grp][lane] = s2;       // per-group buffer

    // out[row][lane] = b2 + sum_k w2[lane][k] * s2[k]
    float acc = sb2[lane];
#pragma unroll
    for (int q = 0; q < D; ++q) acc += sw2[lane*33 + q] * s2sh[grp][q];
    out[(size_t)row * D + lane] = acc;
}

// ---------------------------------------------------------------------------
extern "C" void kernel_launch(void* const* d_in, const int* in_sizes, int n_in,
                              void* d_out, int out_size, void* d_ws, size_t ws_size,
                              hipStream_t stream)
{
    const float* state  = (const float*)d_in[0];
    const float* left   = (const float*)d_in[1];
    const float* adj    = (const float*)d_in[2];
    const float* w3     = (const float*)d_in[3];
    const float* b3     = (const float*)d_in[4];
    const float* attn_w = (const float*)d_in[5];
    const float* w4     = (const float*)d_in[6];
    const float* b4     = (const float*)d_in[7];
    const float* w1     = (const float*)d_in[8];
    const float* b1     = (const float*)d_in[9];
    const float* w_ih   = (const float*)d_in[10];
    // d_in[11] = w_hh: unused by the reference math (only b_hh enters gates)
    const float* b_ih   = (const float*)d_in[12];
    const float* b_hh   = (const float*)d_in[13];
    const float* ln_g   = (const float*)d_in[14];
    const float* ln_b   = (const float*)d_in[15];
    const float* w2     = (const float*)d_in[16];
    const float* b2     = (const float*)d_in[17];
    float* out = (float*)d_out;

    // workspace layout (~21 MB total)
    float* g    = (float*)d_ws;                 // ROWS*D
    float* h    = g  + (size_t)ROWS * D;        // ROWS*D
    float* st   = h  + (size_t)ROWS * D;        // ROWS*D
    float* s_l  = st + (size_t)ROWS * D;        // ROWS
    float* s_r  = s_l + ROWS;                   // ROWS
    float* w4t  = s_r + ROWS;                   // NROW*D
    float* psum = w4t + (size_t)NROW * D;       // F_*16*D
    int*   nzc  = (int*)(psum + F_ * 16 * D);   // ROWS int
    unsigned short* nzi = (unsigned short*)(nzc + ROWS); // ROWS*CAP u16

    k1_g    <<<dim3(ROWS/8 + (D*NROW+255)/256), dim3(256), 0, stream>>>(
                state, left, w3, b3, attn_w, w4, g, s_l, s_r, w4t);
    k2_scan <<<dim3(ROWS/4),  dim3(256), 0, stream>>>(adj, s_l, s_r, w4t, b4, h, nzc, nzi);
    k3a_psum<<<dim3(F_, 16),  dim3(256), 0, stream>>>(h, psum);
    k3b_st  <<<dim3(ROWS/8),  dim3(256), 0, stream>>>(h, g, psum, w1, b1, st);
    k4_final<<<dim3(ROWS/8),  dim3(256), 0, stream>>>(st, nzc, nzi, w_ih, b_ih, b_hh,
                                                      ln_g, ln_b, w2, b2, out);
}

// Round 4
// 131.451 us; speedup vs baseline: 3.2192x; 1.0784x over previous
//
#include <hip/hip_runtime.h>
#include <math.h>

#define F_    16
#define NROW  2000
#define NL    500
#define D     32
#define ROWS  (F_*NROW)   // 32000
#define SLOPE 0.2f
#define CAP   128         // global nz capacity per row (mean ~40)
#define LCAP  256         // LDS nz capacity per row

// ---------------- K1: g = x@w3^T+b3 ; s_l,s_r ; (+w4 transpose blocks) ------
__global__ __launch_bounds__(256) void k1_g(
    const float* __restrict__ state, const float* __restrict__ left,
    const float* __restrict__ w3, const float* __restrict__ b3,
    const float* __restrict__ attn_w, const float* __restrict__ w4,
    float* __restrict__ g, float* __restrict__ s_l, float* __restrict__ s_r,
    float* __restrict__ w4t)
{
    int bid = blockIdx.x;
    int t = threadIdx.x;
    if (bid >= ROWS/8) {           // transpose tail: w4t[j][o] = w4[o][j]
        int k = (bid - ROWS/8) * 256 + t;
        if (k < D * NROW) {
            int o = k / NROW, j = k - o * NROW;
            w4t[j * D + o] = w4[k];
        }
        return;
    }
    __shared__ float sw3[D*33];
    __shared__ float sb3[D], sal[D], sar[D];
    for (int k = t; k < D*D; k += 256) sw3[(k>>5)*33 + (k&31)] = w3[k];
    if (t < D) { sb3[t] = b3[t]; sal[t] = attn_w[t]; sar[t] = attn_w[D + t]; }
    __syncthreads();
    int grp = t >> 5, lane = t & 31;
    int row = bid * 8 + grp;
    int b = row / NROW, i = row - b * NROW;
    const float* xrow = (i < NL) ? (left  + ((size_t)b * NL + i) * D)
                                 : (state + ((size_t)b * (NROW - NL) + (i - NL)) * D);
    float x = xrow[lane];
    float acc = sb3[lane];
#pragma unroll
    for (int k = 0; k < D; ++k)
        acc += __shfl(x, k, 32) * sw3[lane*33 + k];
    g[(size_t)row * D + lane] = acc;
    float pl = acc * sal[lane], pr = acc * sar[lane];
#pragma unroll
    for (int m = 16; m >= 1; m >>= 1) {
        pl += __shfl_xor(pl, m, 32);
        pr += __shfl_xor(pr, m, 32);
    }
    if (lane == 0) { s_l[row] = pl; s_r[row] = pr; }
}

// ---------------- K2: stream mask once: compact nz, compute h ----------------
// wave-per-row. All 8 dwordx4 loads hoisted ahead of the ballot machinery
// (8 outstanding HBM loads/wave); compaction via 4 INDEPENDENT ballots/round
// with a scalar-only carry chain.
__global__ __launch_bounds__(256) void k2_scan(
    const float* __restrict__ adj,
    const float* __restrict__ s_l, const float* __restrict__ s_r,
    const float* __restrict__ w4t, const float* __restrict__ b4,
    float* __restrict__ h, int* __restrict__ nzc, unsigned short* __restrict__ nzi)
{
    __shared__ int   sh_j[4][LCAP];
    __shared__ float sh_e[4][LCAP];
    int t = threadIdx.x;
    int w = t >> 6, lane = t & 63;
    int row = blockIdx.x * 4 + w;
    int b = row / NROW, i = row - b * NROW;
    int r = i & 15;
    const float4* mrow = reinterpret_cast<const float4*>(adj + (size_t)row * NROW);

    // ---- phase 0: issue ALL row loads up front (full MLP) ----
    float4 v[8];
#pragma unroll
    for (int it = 0; it < 8; ++it) {
        int idx4 = it * 64 + lane;
        v[it] = make_float4(0.f, 0.f, 0.f, 0.f);
        if (idx4 < NROW/4) v[it] = mrow[idx4];
    }

    // ---- phase 1: compaction, 4 independent ballots per round ----
    unsigned long long lmask = (1ull << lane) - 1ull;
    int cnt = 0;
#pragma unroll
    for (int it = 0; it < 8; ++it) {
        bool p0 = (v[it].x != 0.f), p1 = (v[it].y != 0.f);
        bool p2 = (v[it].z != 0.f), p3 = (v[it].w != 0.f);
        unsigned long long m0 = __ballot(p0), m1 = __ballot(p1);
        unsigned long long m2 = __ballot(p2), m3 = __ballot(p3);
        int t0 = __popcll(m0), t1 = __popcll(m1), t2 = __popcll(m2), t3 = __popcll(m3);
        int base = (it * 64 + lane) * 4;
        if (p0) { int pos = cnt + __popcll(m0 & lmask);
                  if (pos < LCAP) sh_j[w][pos] = base; }
        if (p1) { int pos = cnt + t0 + __popcll(m1 & lmask);
                  if (pos < LCAP) sh_j[w][pos] = base + 1; }
        if (p2) { int pos = cnt + t0 + t1 + __popcll(m2 & lmask);
                  if (pos < LCAP) sh_j[w][pos] = base + 2; }
        if (p3) { int pos = cnt + t0 + t1 + t2 + __popcll(m3 & lmask);
                  if (pos < LCAP) sh_j[w][pos] = base + 3; }
        cnt += t0 + t1 + t2 + t3;
    }
    if (cnt > LCAP) cnt = LCAP;

    // ---- phase 2: e values (gathers are L1/L2-resident) ----
    const float* slb = s_l + (size_t)b * NROW;
    const float* srr = s_r + (size_t)r * NROW;
    for (int k = lane; k < cnt; k += 64) {
        int j = sh_j[w][k];
        float e = slb[j] + srr[j];
        sh_e[w][k] = (e > 0.f) ? e : SLOPE * e;
    }

    // ---- phase 3: h[row][o] = lrelu(sum_k e_k * w4t[j_k][o] + b4[o]) ----
    int o = lane & 31, half = lane >> 5;
    float acc = 0.f;
    for (int k = half; k < cnt; k += 2)
        acc += sh_e[w][k] * w4t[sh_j[w][k] * D + o];
    acc += __shfl_xor(acc, 32, 64);
    if (lane < 32) {
        float hv = acc + b4[o];
        h[(size_t)row * D + o] = (hv > 0.f) ? hv : SLOPE * hv;
    }

    // ---- phase 4: persist nz list for the agg pass ----
    int cc = (cnt < CAP) ? cnt : CAP;
    for (int k = lane; k < cc; k += 64)
        nzi[(size_t)row * CAP + k] = (unsigned short)sh_j[w][k];
    if (lane == 0) nzc[row] = cc;
}

// ---------------- K3a: partial sums of exp(h), 16 slices x 16 batches --------
__global__ __launch_bounds__(256) void k3a_psum(const float* __restrict__ h,
                                                float* __restrict__ psum)
{
    int b = blockIdx.x, slice = blockIdx.y;
    int t = threadIdx.x;
    int o = t & 31, ti = t >> 5;   // 8 row-groups
    int base = slice * 125;
    float s = 0.f;
    for (int i = base + ti; i < base + 125; i += 8)
        s += expf(h[((size_t)b * NROW + i) * D + o]);
    __shared__ float red[8][D];
    red[ti][o] = s;
    __syncthreads();
    if (t < D) {
        float tot = 0.f;
#pragma unroll
        for (int k = 0; k < 8; ++k) tot += red[k][t];
        psum[((size_t)b * 16 + slice) * D + t] = tot;
    }
}

// ---------------- K3b: st = (softmax(h)*g) @ w1^T + b1 -----------------------
__global__ __launch_bounds__(256) void k3b_st(
    const float* __restrict__ h, const float* __restrict__ g,
    const float* __restrict__ psum,
    const float* __restrict__ w1, const float* __restrict__ b1,
    float* __restrict__ st)
{
    __shared__ float sw1[D*33], sb1[D], ssum[D];
    int t = threadIdx.x;
    int bid = blockIdx.x;
    int b = bid / 250;
    for (int k = t; k < D*D; k += 256) sw1[(k>>5)*33 + (k&31)] = w1[k];
    if (t < D) {
        sb1[t] = b1[t];
        float tot = 0.f;
#pragma unroll
        for (int s = 0; s < 16; ++s) tot += psum[((size_t)b * 16 + s) * D + t];
        ssum[t] = tot;
    }
    __syncthreads();
    int grp = t >> 5, lane = t & 31;
    size_t row = (size_t)bid * 8 + grp;
    float p = (expf(h[row * D + lane]) / ssum[lane]) * g[row * D + lane];
    float acc = sb1[lane];
#pragma unroll
    for (int k = 0; k < D; ++k)
        acc += __shfl(p, k, 32) * sw1[lane*33 + k];
    st[row * D + lane] = acc;
}

// ---------------- K4: agg gather + LN + gates + c1 + final matvec ------------
__global__ __launch_bounds__(256) void k4_final(
    const float* __restrict__ st,
    const int* __restrict__ nzc, const unsigned short* __restrict__ nzi,
    const float* __restrict__ w_ih, const float* __restrict__ b_ih,
    const float* __restrict__ b_hh,
    const float* __restrict__ ln_g, const float* __restrict__ ln_b,
    const float* __restrict__ w2, const float* __restrict__ b2,
    float* __restrict__ out)
{
    __shared__ float swih[96*33];          // padded
    __shared__ float sw2[D*33];            // padded
    __shared__ float sbg[96];
    __shared__ float sb2[D], slg[D], slb[D];
    __shared__ unsigned short jl[8][CAP];
    __shared__ float aggsh[8][D];
    __shared__ float s2sh[8][D];

    int t = threadIdx.x;
    for (int k = t; k < 96*D; k += 256) swih[(k/D)*33 + (k%D)] = w_ih[k];
    for (int k = t; k < D*D;  k += 256) sw2 [(k/D)*33 + (k%D)] = w2[k];
    if (t < 96) sbg[t] = b_ih[t] + b_hh[t];
    if (t < D) { sb2[t] = b2[t]; slg[t] = ln_g[t]; slb[t] = ln_b[t]; }

    int grp = t >> 5, lane = t & 31;
    int row = blockIdx.x * 8 + grp;
    int b = row / NROW;
    int cnt = nzc[row];
    const unsigned short* lst = nzi + (size_t)row * CAP;
    for (int k = lane; k < cnt; k += 32) jl[grp][k] = lst[k];
    __syncthreads();   // for the cooperatively staged weights

    // agg[lane] = sum over nz rows of st[b][j][lane]  (coalesced 128B loads,
    // 8-deep unroll for outstanding L2 loads)
    const float* stb = st + (size_t)b * NROW * D;
    float agg = 0.f;
    int k = 0;
    for (; k + 8 <= cnt; k += 8) {
        int j0 = jl[grp][k],   j1 = jl[grp][k+1], j2 = jl[grp][k+2], j3 = jl[grp][k+3];
        int j4 = jl[grp][k+4], j5 = jl[grp][k+5], j6 = jl[grp][k+6], j7 = jl[grp][k+7];
        float a0 = stb[j0*D + lane], a1 = stb[j1*D + lane];
        float a2 = stb[j2*D + lane], a3 = stb[j3*D + lane];
        float a4 = stb[j4*D + lane], a5 = stb[j5*D + lane];
        float a6 = stb[j6*D + lane], a7 = stb[j7*D + lane];
        agg += ((a0 + a1) + (a2 + a3)) + ((a4 + a5) + (a6 + a7));
    }
    for (; k < cnt; ++k) agg += stb[jl[grp][k]*D + lane];

    float sv = st[(size_t)row * D + lane];

    // layernorm stats across the 32-lane group
    float sum = sv;
#pragma unroll
    for (int m = 16; m >= 1; m >>= 1) sum += __shfl_xor(sum, m, 32);
    float mean = sum * (1.f / D);
    float dd = sv - mean;
    float vs = dd * dd;
#pragma unroll
    for (int m = 16; m >= 1; m >>= 1) vs += __shfl_xor(vs, m, 32);
    float inv = 1.f / sqrtf(vs * (1.f / D) + 1e-6f);
    float nx = slg[lane] * dd * inv + slb[lane];

    aggsh[grp][lane] = agg;     // per-group buffer: within-wave ordering only

    // gates: lane q computes rows q, q+32, q+64 of w_ih (LDS broadcast reads)
    float gi = sbg[lane], gf = sbg[lane + 32], gg = sbg[lane + 64];
#pragma unroll
    for (int d = 0; d < D; ++d) {
        float a = aggsh[grp][d];
        gi += swih[lane*33 + d]      * a;
        gf += swih[(lane+32)*33 + d] * a;
        gg += swih[(lane+64)*33 + d] * a;
    }
    float ig  = 1.f / (1.f + expf(-gi));
    float fg  = 1.f / (1.f + expf(-gf));
    float g_g = tanhf(gg);
    float s2  = sv + fg * nx + ig * g_g;

    s2sh[grp][lane] = s2;       // per-group buffer

    // out[row][lane] = b2 + sum_k w2[lane][k] * s2[k]
    float acc = sb2[lane];
#pragma unroll
    for (int q = 0; q < D; ++q) acc += sw2[lane*33 + q] * s2sh[grp][q];
    out[(size_t)row * D + lane] = acc;
}

// ---------------------------------------------------------------------------
extern "C" void kernel_launch(void* const* d_in, const int* in_sizes, int n_in,
                              void* d_out, int out_size, void* d_ws, size_t ws_size,
                              hipStream_t stream)
{
    const float* state  = (const float*)d_in[0];
    const float* left   = (const float*)d_in[1];
    const float* adj    = (const float*)d_in[2];
    const float* w3     = (const float*)d_in[3];
    const float* b3     = (const float*)d_in[4];
    const float* attn_w = (const float*)d_in[5];
    const float* w4     = (const float*)d_in[6];
    const float* b4     = (const float*)d_in[7];
    const float* w1     = (const float*)d_in[8];
    const float* b1     = (const float*)d_in[9];
    const float* w_ih   = (const float*)d_in[10];
    // d_in[11] = w_hh: unused by the reference math (only b_hh enters gates)
    const float* b_ih   = (const float*)d_in[12];
    const float* b_hh   = (const float*)d_in[13];
    const float* ln_g   = (const float*)d_in[14];
    const float* ln_b   = (const float*)d_in[15];
    const float* w2     = (const float*)d_in[16];
    const float* b2     = (const float*)d_in[17];
    float* out = (float*)d_out;

    // workspace layout (~21 MB total)
    float* g    = (float*)d_ws;                 // ROWS*D
    float* h    = g  + (size_t)ROWS * D;        // ROWS*D
    float* st   = h  + (size_t)ROWS * D;        // ROWS*D
    float* s_l  = st + (size_t)ROWS * D;        // ROWS
    float* s_r  = s_l + ROWS;                   // ROWS
    float* w4t  = s_r + ROWS;                   // NROW*D
    float* psum = w4t + (size_t)NROW * D;       // F_*16*D
    int*   nzc  = (int*)(psum + F_ * 16 * D);   // ROWS int
    unsigned short* nzi = (unsigned short*)(nzc + ROWS); // ROWS*CAP u16

    k1_g    <<<dim3(ROWS/8 + (D*NROW+255)/256), dim3(256), 0, stream>>>(
                state, left, w3, b3, attn_w, w4, g, s_l, s_r, w4t);
    k2_scan <<<dim3(ROWS/4),  dim3(256), 0, stream>>>(adj, s_l, s_r, w4t, b4, h, nzc, nzi);
    k3a_psum<<<dim3(F_, 16),  dim3(256), 0, stream>>>(h, psum);
    k3b_st  <<<dim3(ROWS/8),  dim3(256), 0, stream>>>(h, g, psum, w1, b1, st);
    k4_final<<<dim3(ROWS/8),  dim3(256), 0, stream>>>(st, nzc, nzi, w_ih, b_ih, b_hh,
                                                      ln_g, ln_b, w2, b2, out);
}